// Round 1
// baseline (83.891 us; speedup 1.0000x reference)
//
#include <hip/hip_runtime.h>
#include <math.h>

// HOG: x (N,3,224,224) f32 -> out (N, 9*28*28) f32
// gx = sobelX(sum_c x), gy = sobelY(sum_c x)   [SAME zero pad]
// mag = sqrt(gx^2+gy^2); bin = floor(|atan2(gx,gy)|/pi*8) in [0,8]
// Bin via comparison network (gy <= mag*cos(k*pi/8)), guarded atan2f fallback
// within 1e-4*mag of any boundary -> binning provably matches the reference.
//
// R5 structure: ONE cell row per block (256 thr, 28x64=1792 blocks).
//  - LDS tile only 10 rows x 232 cols = 9.3 KB (was 33 KB): latency theory says
//    the old 512-thr/33KB blocks (<=4/CU, 3.5 avg) could not hide the
//    stage->barrier->compute chain. Now ~6 blocks/CU co-resident.
//  - Cell reduction via 8-lane __shfl_down tree (cells are 8 aligned lanes,
//    never crossing the 32-lane active boundary of wave 3) -> no h2 LDS
//    array, no second barrier, no third phase.
//  - Staging: 560 float4 chunks over 256 threads = 3 unrolled iters, first
//    two unconditional; all 9 global loads in flight before one waitcnt.

namespace {
constexpr int Himg = 224;
constexpr int Wimg = 224;
constexpr int NCELL = 28;   // 224/8
constexpr int BINS  = 9;
constexpr int ROWS  = 10;   // 8 image rows + halo above/below
constexpr int LDSW  = 232;  // 4 left pad + 224 + 4 right pad (16B-aligned stores)
constexpr int NCHUNK = ROWS * 56;  // 560 float4 chunks per tile

__global__ __launch_bounds__(256, 6) void hog_kernel(const float* __restrict__ x,
                                                     float* __restrict__ out) {
    const int n  = blockIdx.y;   // sample
    const int cr = blockIdx.x;   // cell row 0..27
    const int t  = threadIdx.x;  // 0..255

    __shared__ float s[ROWS][LDSW];        // channel-sum tile, col index = w + 4

    if (t < ROWS * 8) {                    // zero left/right halo pads
        int r = t >> 3;
        int c = t & 7;
        int col = (c < 4) ? c : (224 + c);
        s[r][col] = 0.0f;
    }

    const int h0 = cr * 8 - 1;             // image row of LDS row 0
    const float* xb = x + (size_t)n * 3 * Himg * Wimg;

    // Stage: 560 float4 chunks over 256 threads, 3 unrolled iters (last predicated).
    float4 va[3];
    int    lofs[3];
    bool   act[3];
#pragma unroll
    for (int k = 0; k < 3; ++k) {
        int idx = t + 256 * k;
        bool pred = (k < 2) || (idx < NCHUNK);
        int r = pred ? (idx / 56) : 0;
        int q = idx - r * 56;
        int w = q * 4;
        int h = h0 + r;
        act[k]  = pred;
        lofs[k] = r * LDSW + 4 + w;        // flat LDS float offset
        float4 v = make_float4(0.f, 0.f, 0.f, 0.f);
        if (pred && h >= 0 && h < Himg) {
            const float* r0 = xb + (size_t)h * Wimg + w;
            float4 a  = *(const float4*)(r0);
            float4 b  = *(const float4*)(r0 + Himg * Wimg);
            float4 c4 = *(const float4*)(r0 + 2 * Himg * Wimg);
            v.x = a.x + b.x + c4.x;
            v.y = a.y + b.y + c4.y;
            v.z = a.z + b.z + c4.z;
            v.w = a.w + b.w + c4.w;
        }
        va[k] = v;
    }
#pragma unroll
    for (int k = 0; k < 3; ++k)
        if (act[k]) *(float4*)&((float*)s)[lofs[k]] = va[k];
    __syncthreads();

    const float PI_F = 3.14159265358979323846f;
    const float CK[8] = {0.92387953f, 0.70710678f, 0.38268343f, 0.0f,
                         -0.38268343f, -0.70710678f, -0.92387953f, -1.0f};

    if (t < 224) {
        const int w = t;                   // image column
        float ml = s[0][3 + w], mc = s[0][4 + w], mr = s[0][5 + w];
        float zl = s[1][3 + w], zc = s[1][4 + w], zr = s[1][5 + w];
        float acc[BINS];
#pragma unroll
        for (int j = 0; j < BINS; ++j) acc[j] = 0.0f;

#pragma unroll
        for (int i = 0; i < 8; ++i) {
            float pl = s[i + 2][3 + w];
            float pc = s[i + 2][4 + w];
            float pr = s[i + 2][5 + w];

            float gx = (mr - ml) + 2.0f * (zr - zl) + (pr - pl);
            float gy = (pl + 2.0f * pc + pr) - (ml + 2.0f * mc + mr);
            float mag = sqrtf(gx * gx + gy * gy);

            float negy = -gy;
            int bin = 0;
            float guard = 1e30f;
#pragma unroll
            for (int j = 0; j < 8; ++j) {
                float sj = fmaf(mag, CK[j], negy);
                bin += (sj >= 0.0f) ? 1 : 0;
                guard = fminf(guard, fabsf(sj));
            }
            if (guard < mag * 1e-4f) {     // rare: exact reference pipeline
                float ang = fabsf(atan2f(gx, gy));
                bin = (int)(ang / PI_F * 8.0f);
                bin = bin > 8 ? 8 : bin;
            }
#pragma unroll
            for (int j = 0; j < BINS; ++j) acc[j] += (bin == j) ? mag : 0.0f;

            ml = zl; mc = zc; mr = zr;
            zl = pl; zc = pc; zr = pr;
        }

        // 8-lane tree reduction within each cell (lanes w..w+7, 8-aligned,
        // never crossing the 32-lane active boundary of the last wave).
#pragma unroll
        for (int j = 0; j < BINS; ++j) {
            float v = acc[j];
            v += __shfl_down(v, 4);
            v += __shfl_down(v, 2);
            v += __shfl_down(v, 1);
            acc[j] = v;
        }
        if ((w & 7) == 0) {
            const int cw = w >> 3;
#pragma unroll
            for (int j = 0; j < BINS; ++j)
                out[((size_t)n * BINS + j) * (NCELL * NCELL) + (size_t)cr * NCELL + cw] = acc[j];
        }
    }
}
}  // namespace

extern "C" void kernel_launch(void* const* d_in, const int* in_sizes, int n_in,
                              void* d_out, int out_size, void* d_ws, size_t ws_size,
                              hipStream_t stream) {
    const float* x = (const float*)d_in[0];
    float* out = (float*)d_out;
    const int N = in_sizes[0] / (3 * Himg * Wimg);
    dim3 grid(NCELL, N);
    hog_kernel<<<grid, 256, 0, stream>>>(x, out);
}